// Round 1
// 317.402 us; speedup vs baseline: 1.1238x; 1.1238x over previous
//
#include <hip/hip_runtime.h>
#include <hip/hip_bf16.h>
#include <stdint.h>

typedef __bf16 bf16;
typedef __attribute__((ext_vector_type(8))) __bf16 bf16x8;
typedef __attribute__((ext_vector_type(2))) __bf16 bf16x2;
typedef __attribute__((ext_vector_type(4))) float f32x4;
typedef __attribute__((ext_vector_type(4))) unsigned int u32x4;

#define NH 16
#define DH 64
#define POOL 8
#define BATCH 4
#define SEQ 4096
#define DIMV 1024
#define QKV_N (3*DIMV)
#define M_TOTAL (BATCH*SEQ)
#define SCALE_F 0.125f
// agent buffer holds SUMS over 512 t (from GEMM1-epilogue atomics);
// consumers fold mean (1/512) into the pre-softmax dot: exact.
#define AGS_F (SCALE_F / 512.0f)
#define BH (BATCH*NH)              // 64
#define QKVSZ ((size_t)BH*SEQ*DH)  // elems per q/k/v plane
#define TCH 16                     // t-split chunks for stage1
#define TCL (SEQ/TCH)              // 256 t per chunk
#define HP 128                     // h*p combined dim for P2/W2

#define AS1(p) ((const __attribute__((address_space(1))) void*)(p))
#define AS3(p) ((__attribute__((address_space(3))) void*)(p))
typedef const __attribute__((address_space(3))) char* lds_cp;

// ---------------- elementwise fp32 -> bf16 (8 elems/thread) ----------------
__global__ void convert_x(const float* __restrict__ in, bf16* __restrict__ out) {
  size_t i = ((size_t)blockIdx.x * 256 + threadIdx.x) * 8;
  float4 f0 = *(const float4*)(in + i);
  float4 f1 = *(const float4*)(in + i + 4);
  bf16x8 o;
  o[0] = (bf16)f0.x; o[1] = (bf16)f0.y; o[2] = (bf16)f0.z; o[3] = (bf16)f0.w;
  o[4] = (bf16)f1.x; o[5] = (bf16)f1.y; o[6] = (bf16)f1.z; o[7] = (bf16)f1.w;
  *(bf16x8*)(out + i) = o;
}

// ---------------- transpose fp32 [R][C] -> bf16 [C][R] ----------------
__global__ void transpose_f32_bf16(const float* __restrict__ in, bf16* __restrict__ out,
                                   int R, int C) {
  __shared__ float tile[32][33];
  int c0 = blockIdx.x * 32, r0 = blockIdx.y * 32;
  int tx = threadIdx.x & 31, ty = threadIdx.x >> 5;
  for (int i = ty; i < 32; i += 8)
    tile[i][tx] = in[(size_t)(r0 + i) * C + c0 + tx];
  __syncthreads();
  for (int i = ty; i < 32; i += 8)
    out[(size_t)(c0 + i) * R + r0 + tx] = (bf16)tile[tx][i];
}

// ============================================================================
// GEMM1: 256x256 tile, BK=64, 8 waves, 8-phase schedule (T2+T3+T4+T5).
//   qkv = xb @ WqkvT^T, scattered to q/k/v planes; q-tiles also accumulate
//   agent pooling sums (fp32 atomics).
// LDS: 2 bufs x {A,B} x 2 halves x [128][64] bf16 = 128 KiB (1 block/CU).
// Swizzle: 16B slot s within a 128B row stored at s^(row&7); staged via
//   pre-swizzled GLOBAL source column (gload_lds dest stays linear), read
//   with the same XOR -> conflict-free ds_read_b128 (rule #21 both-sides).
// Counted vmcnt(4) only at phase 4/8 boundaries; ds_read via inline asm so
//   the compiler's waitcnt pass cannot drain the pipeline; sched_barrier(0)
//   after each lgkmcnt(0) (rule #18).
// ============================================================================
__global__ __launch_bounds__(512, 2)
void gemm1_qkv(const bf16* __restrict__ A, const bf16* __restrict__ B,
               bf16* __restrict__ qkvOut, float* __restrict__ agentSum) {
  constexpr int K1 = DIMV;       // 1024
  constexpr int NI = K1 / 128;   // 8 pipeline iterations (2 K-tiles each)

  __shared__ __align__(16) bf16 LA[2][2][8192];   // [buf][half][128*64]
  __shared__ __align__(16) bf16 LB[2][2][8192];

  const int tid  = threadIdx.x;
  const int w    = tid >> 6;
  const int lane = tid & 63;
  const int wm = (w >> 2) * 128;         // 2 M-waves x 4 N-waves
  const int wn = (w & 3) * 64;

  // bijective XCD swizzle (768 % 8 == 0)
  const int bid = blockIdx.x;
  const int swz = (bid & 7) * 96 + (bid >> 3);
  const int m0 = (swz / 12) * 256;
  const int n0 = (swz % 12) * 256;

  // staging: thread t covers (row rT + 64*e + 128*half, 16B slot t&7);
  // source column pre-swizzled so linear LDS dest realizes slot^(row&7).
  const int rT  = tid >> 3;
  const int csT = (((tid & 7) ^ (rT & 7)) << 3);
  const bf16* Ag = A + (size_t)(m0 + rT) * K1 + csT;
  const bf16* Bg = B + (size_t)(n0 + rT) * K1 + csT;

  // ds_read lane constants: row rA within 16-row frag, k-group C, xor rA&7
  const int rA = lane & 15, C = lane >> 4, xr = rA & 7;
  const unsigned s0 = (unsigned)(((0 * 4 + C) ^ xr) << 4);   // ks=0 slot byte
  const unsigned s1 = (unsigned)(((1 * 4 + C) ^ xr) << 4);   // ks=1 slot byte
  const unsigned aoff = (unsigned)((wm + rA) << 7);          // folds half+row
  const unsigned boff = (unsigned)((wn + rA) << 7);

  f32x4 acc[8][4] = {};
  u32x4 aR[4][2], bR[4][2];

#define STG(arr, Gp, half, kofs) do {                                         \
    const bf16* _s = (Gp) + (size_t)((half) * 128) * K1 + (kofs);             \
    char* _d = (char*)&arr[half][0] + (w << 10);                              \
    __builtin_amdgcn_global_load_lds(AS1(_s), AS3(_d), 16, 0, 0);             \
    __builtin_amdgcn_global_load_lds(AS1(_s + 64 * K1), AS3(_d + 8192), 16, 0, 0); \
  } while (0)

#define DSR0(d, p)    asm volatile("ds_read_b128 %0, %1" : "=v"(d) : "v"(p))
#define DSR(d, p, o)  asm volatile("ds_read_b128 %0, %1 offset:" o : "=v"(d) : "v"(p))

#define READS_A(LAb, qm) do {                                                 \
    lds_cp _p0 = (lds_cp)(const char*)&LAb[0][0] + aoff + s0 + (qm) * 8192;   \
    lds_cp _p1 = (lds_cp)(const char*)&LAb[0][0] + aoff + s1 + (qm) * 8192;   \
    DSR0(aR[0][0], _p0); DSR(aR[1][0], _p0, "2048");                          \
    DSR(aR[2][0], _p0, "4096"); DSR(aR[3][0], _p0, "6144");                   \
    DSR0(aR[0][1], _p1); DSR(aR[1][1], _p1, "2048");                          \
    DSR(aR[2][1], _p1, "4096"); DSR(aR[3][1], _p1, "6144");                   \
  } while (0)

#define READS_B01(LBb) do {                                                   \
    lds_cp _p0 = (lds_cp)(const char*)&LBb[0][0] + boff + s0;                 \
    lds_cp _p1 = (lds_cp)(const char*)&LBb[0][0] + boff + s1;                 \
    DSR0(bR[0][0], _p0); DSR(bR[1][0], _p0, "2048");                          \
    DSR0(bR[0][1], _p1); DSR(bR[1][1], _p1, "2048");                          \
  } while (0)

#define READS_B23(LBb) do {                                                   \
    lds_cp _p0 = (lds_cp)(const char*)&LBb[0][0] + boff + s0;                 \
    lds_cp _p1 = (lds_cp)(const char*)&LBb[0][0] + boff + s1;                 \
    DSR(bR[2][0], _p0, "4096"); DSR(bR[3][0], _p0, "6144");                   \
    DSR(bR[2][1], _p1, "4096"); DSR(bR[3][1], _p1, "6144");                   \
  } while (0)

#define MFMA_Q(qm, qn) do {                                                   \
    asm volatile("s_waitcnt lgkmcnt(0)");                                     \
    __builtin_amdgcn_sched_barrier(0);                                        \
    __builtin_amdgcn_s_setprio(1);                                            \
    _Pragma("unroll")                                                         \
    for (int il = 0; il < 4; ++il)                                            \
      _Pragma("unroll")                                                       \
      for (int jj = 0; jj < 2; ++jj) {                                        \
        f32x4& ac = acc[(qm) * 4 + il][(qn) * 2 + jj];                        \
        ac = __builtin_amdgcn_mfma_f32_16x16x32_bf16(                         \
            __builtin_bit_cast(bf16x8, aR[il][0]),                            \
            __builtin_bit_cast(bf16x8, bR[(qn) * 2 + jj][0]), ac, 0, 0, 0);   \
        ac = __builtin_amdgcn_mfma_f32_16x16x32_bf16(                         \
            __builtin_bit_cast(bf16x8, aR[il][1]),                            \
            __builtin_bit_cast(bf16x8, bR[(qn) * 2 + jj][1]), ac, 0, 0, 0);   \
      }                                                                       \
    __builtin_amdgcn_s_setprio(0);                                            \
    __builtin_amdgcn_sched_barrier(0);                                        \
  } while (0)

#define BAR __builtin_amdgcn_s_barrier()

  // prologue: tile0 (A+B) -> buf0; tile1 B -> buf1   (12 issues)
  STG(LA[0], Ag, 0, 0); STG(LA[0], Ag, 1, 0);
  STG(LB[0], Bg, 0, 0); STG(LB[0], Bg, 1, 0);
  STG(LB[1], Bg, 0, 64); STG(LB[1], Bg, 1, 64);
  asm volatile("s_waitcnt vmcnt(4)");    // buf0 tile landed; buf1 B in flight
  __builtin_amdgcn_sched_barrier(0);
  BAR;

  int kk = 0;
  for (int i = 0; i < NI - 1; ++i, kk += 128) {
    // ---- phases 1-4: consume buf0 (tile 2i) ----
    READS_A(LA[0], 0); READS_B01(LB[0]);
    STG(LA[1], Ag, 0, kk + 64);          // ph1: buf1.A0 <- tile 2i+1
    BAR; MFMA_Q(0, 0); BAR;
    READS_B23(LB[0]);
    STG(LA[1], Ag, 1, kk + 64);          // ph2: buf1.A1 <- tile 2i+1
    BAR; MFMA_Q(0, 1); BAR;
    READS_A(LA[0], 1);
    STG(LB[0], Bg, 0, kk + 128);         // ph3: buf0.B0 <- tile 2i+2
    BAR; MFMA_Q(1, 0); BAR;
    STG(LB[0], Bg, 1, kk + 128);         // ph4: buf0.B1 <- tile 2i+2
    BAR; MFMA_Q(1, 1);
    asm volatile("s_waitcnt vmcnt(4)");  // buf1 tile 2i+1 landed
    __builtin_amdgcn_sched_barrier(0);
    BAR;
    // ---- phases 5-8: consume buf1 (tile 2i+1) ----
    READS_A(LA[1], 0); READS_B01(LB[1]);
    STG(LA[0], Ag, 0, kk + 128);         // ph5: buf0.A0 <- tile 2i+2
    BAR; MFMA_Q(0, 0); BAR;
    READS_B23(LB[1]);
    STG(LA[0], Ag, 1, kk + 128);         // ph6: buf0.A1 <- tile 2i+2
    BAR; MFMA_Q(0, 1); BAR;
    READS_A(LA[1], 1);
    STG(LB[1], Bg, 0, kk + 192);         // ph7: buf1.B0 <- tile 2i+3
    BAR; MFMA_Q(1, 0); BAR;
    STG(LB[1], Bg, 1, kk + 192);         // ph8: buf1.B1 <- tile 2i+3
    BAR; MFMA_Q(1, 1);
    asm volatile("s_waitcnt vmcnt(4)");  // buf0 tile 2i+2 landed
    __builtin_amdgcn_sched_barrier(0);
    BAR;
  }
  // ---- tail iteration: buf0 = tile NT-2, buf1 = tile NT-1 ----
  READS_A(LA[0], 0); READS_B01(LB[0]);
  STG(LA[1], Ag, 0, kk + 64);            // last A halves of tile NT-1
  BAR; MFMA_Q(0, 0); BAR;
  READS_B23(LB[0]);
  STG(LA[1], Ag, 1, kk + 64);
  BAR; MFMA_Q(0, 1); BAR;
  READS_A(LA[0], 1);
  BAR; MFMA_Q(1, 0); BAR;
  MFMA_Q(1, 1);
  asm volatile("s_waitcnt vmcnt(0)");    // drain: buf1 tile NT-1 landed
  __builtin_amdgcn_sched_barrier(0);
  BAR;
  READS_A(LA[1], 0); READS_B01(LB[1]);
  BAR; MFMA_Q(0, 0); BAR;
  READS_B23(LB[1]);
  BAR; MFMA_Q(0, 1); BAR;
  READS_A(LA[1], 1);
  BAR; MFMA_Q(1, 0); BAR;
  MFMA_Q(1, 1);

#undef STG
#undef DSR0
#undef DSR
#undef READS_A
#undef READS_B01
#undef READS_B23
#undef MFMA_Q
#undef BAR

  // ---- epilogue: scatter to q/k/v planes (C/D layout col=lane&15,
  //      row=(lane>>4)*4+r); wave owns rows [m0+wm,+128), cols = one 64-d head.
  const int cr = (lane >> 4) * 4;
  const int cc = lane & 15;
  const int ncol  = n0 + wn;             // multiple of 64 -> single (plane,head)
  const int which = ncol >> 10;
  const int hh    = (ncol >> 6) & 15;
  const int rowb  = m0 + wm;
  const int bb_   = rowb >> 12;
  const int tb    = rowb & 4095;
  bf16* Cp = qkvOut + (size_t)which * QKVSZ + (size_t)(bb_ * NH + hh) * SEQ * DH;
#pragma unroll
  for (int i = 0; i < 8; ++i)
#pragma unroll
    for (int j = 0; j < 4; ++j)
#pragma unroll
      for (int r = 0; r < 4; ++r)
        Cp[(size_t)(tb + i * 16 + cr + r) * DH + j * 16 + cc] = (bf16)acc[i][j][r];

  // fused agent pooling (q plane only): all 128 rows lie in one 512-t bucket.
  if (which == 0) {
    const int pp = tb >> 9;
    float* ag = agentSum + ((size_t)(bb_ * NH + hh) * POOL + pp) * DH;
#pragma unroll
    for (int j = 0; j < 4; ++j) {
      float s = 0.f;
#pragma unroll
      for (int i = 0; i < 8; ++i)
        s += acc[i][j][0] + acc[i][j][1] + acc[i][j][2] + acc[i][j][3];
      s += __shfl_xor(s, 16);
      s += __shfl_xor(s, 32);
      if (lane < 16) atomicAdd(&ag[j * 16 + lane], s);
    }
  }
}

// ---------------- MFMA GEMM (legacy 128^2 structure), MODE 2 only ----------
// MODE 2: fp32 out row-major + fp32 bias, B batched per 4096 rows of A.
template <int MODE>
__global__ __launch_bounds__(256)
void gemm_bt(const bf16* __restrict__ A, const bf16* __restrict__ B,
             void* __restrict__ Cv, const float* __restrict__ bias,
             float* __restrict__ agentSum, int M, int N, int K) {
  __shared__ bf16 As[128 * 32];
  __shared__ bf16 Bs[128 * 32];
  const int tid  = threadIdx.x;
  const int w    = tid >> 6;
  const int lane = tid & 63;
  const int m0 = blockIdx.y * 128, n0 = blockIdx.x * 128;
  const int wm = (w & 1) * 64, wn = (w >> 1) * 64;

  const bf16* Bb = (MODE == 2) ? (B + (size_t)(m0 >> 12) * N * K) : B;

  f32x4 acc[4][4] = {};

  const int g0  = w * 2;
  const int rig = lane >> 2;
  const int kcs = (lane & 3) ^ ((rig >> 1) & 3);
  const bf16* Ap0 = A + (size_t)(m0 + g0 * 16 + rig) * K + kcs * 8;
  const bf16* Ap1 = Ap0 + (size_t)16 * K;
  const bf16* Bp0 = Bb + (size_t)(n0 + g0 * 16 + rig) * K + kcs * 8;
  const bf16* Bp1 = Bp0 + (size_t)16 * K;
  bf16* AsW0 = As + g0 * 512;
  bf16* AsW1 = As + (g0 + 1) * 512;
  bf16* BsW0 = Bs + g0 * 512;
  bf16* BsW1 = Bs + (g0 + 1) * 512;

  for (int k0 = 0; k0 < K; k0 += 32) {
    __syncthreads();
    __builtin_amdgcn_global_load_lds(AS1(Ap0 + k0), AS3(AsW0), 16, 0, 0);
    __builtin_amdgcn_global_load_lds(AS1(Ap1 + k0), AS3(AsW1), 16, 0, 0);
    __builtin_amdgcn_global_load_lds(AS1(Bp0 + k0), AS3(BsW0), 16, 0, 0);
    __builtin_amdgcn_global_load_lds(AS1(Bp1 + k0), AS3(BsW1), 16, 0, 0);
    __syncthreads();

    bf16x8 a[4], b[4];
    const int C = lane >> 4;
#pragma unroll
    for (int i = 0; i < 4; ++i) {
      int ar = wm + i * 16 + (lane & 15);
      int sw = C ^ ((ar >> 1) & 3);
      a[i] = *(const bf16x8*)&As[ar * 32 + sw * 8];
    }
#pragma unroll
    for (int j = 0; j < 4; ++j) {
      int br = wn + j * 16 + (lane & 15);
      int sw = C ^ ((br >> 1) & 3);
      b[j] = *(const bf16x8*)&Bs[br * 32 + sw * 8];
    }
#pragma unroll
    for (int i = 0; i < 4; ++i)
#pragma unroll
      for (int j = 0; j < 4; ++j)
        acc[i][j] = __builtin_amdgcn_mfma_f32_16x16x32_bf16(a[i], b[j], acc[i][j], 0, 0, 0);
  }

  const int cr = (lane >> 4) * 4;
  const int cc = lane & 15;
#pragma unroll
  for (int i = 0; i < 4; ++i) {
#pragma unroll
    for (int j = 0; j < 4; ++j) {
      int rowb = m0 + wm + i * 16 + cr;
      if (MODE == 2) {
        float* Cp = (float*)Cv;
        int col = n0 + wn + j * 16 + cc;
        float bb = bias[col];
#pragma unroll
        for (int r = 0; r < 4; ++r)
          Cp[(size_t)(rowb + r) * N + col] = acc[i][j][r] + bb;
      } else {
        bf16* Cp = (bf16*)Cv;
        int nbase = n0 + wn + j * 16;
        int which = nbase >> 10;
        int hh    = (nbase >> 6) & 15;
        int dd    = (nbase & 63) + cc;
        int bb_   = rowb >> 12;
#pragma unroll
        for (int r = 0; r < 4; ++r) {
          int t = (rowb + r) & 4095;
          size_t addr = (size_t)which * QKVSZ +
                        ((size_t)(bb_ * NH + hh) * SEQ + t) * DH + dd;
          Cp[addr] = (bf16)acc[i][j][r];
        }
      }
    }
  }
}

// ---- stage 1 fused: scores + chunk softmax + P@V partial, per (bh, t-chunk) ----
__global__ __launch_bounds__(256)
void stage1_fused(const bf16* __restrict__ k, const bf16* __restrict__ v,
                  const float* __restrict__ agentSum,
                  float* __restrict__ pm, float* __restrict__ pl,
                  float* __restrict__ pva) {
  const int tc = blockIdx.x, bh = blockIdx.y;
  const int tid = threadIdx.x;
  const int t0 = tc * TCL;

  __shared__ float agT[64][8];           // [d][p], scaled by SCALE/512
  __shared__ float se[TCL][9];           // exp(sc-m), pad to 9
  __shared__ float rm[4][8], rl[4][8];
  __shared__ float pr[4][8][64];         // [to][p][d] partial PV

  for (int i = tid; i < 512; i += 256) {
    int p = i >> 6, d = i & 63;
    agT[d][p] = agentSum[(size_t)bh * 512 + i] * AGS_F;
  }
  __syncthreads();

  const bf16* krow = k + ((size_t)bh * SEQ + t0 + tid) * DH;
  float sc[8] = {};
#pragma unroll
  for (int dc = 0; dc < 8; ++dc) {
    bf16x8 k8 = *(const bf16x8*)(krow + dc * 8);
#pragma unroll
    for (int e = 0; e < 8; ++e) {
      float kv = (float)k8[e];
      int d = dc * 8 + e;
      float4 a0 = *(const float4*)&agT[d][0];
      float4 a1 = *(const float4*)&agT[d][4];
      sc[0] += a0.x * kv; sc[1] += a0.y * kv; sc[2] += a0.z * kv; sc[3] += a0.w * kv;
      sc[4] += a1.x * kv; sc[5] += a1.y * kv; sc[6] += a1.z * kv; sc[7] += a1.w * kv;
    }
  }

  float mx[8];
#pragma unroll
  for (int p = 0; p < 8; ++p) mx[p] = sc[p];
#pragma unroll
  for (int o = 32; o; o >>= 1)
#pragma unroll
    for (int p = 0; p < 8; ++p) mx[p] = fmaxf(mx[p], __shfl_xor(mx[p], o));
  if ((tid & 63) == 0)
#pragma unroll
    for (int p = 0; p < 8; ++p) rm[tid >> 6][p] = mx[p];
  __syncthreads();
  float m[8];
#pragma unroll
  for (int p = 0; p < 8; ++p)
    m[p] = fmaxf(fmaxf(rm[0][p], rm[1][p]), fmaxf(rm[2][p], rm[3][p]));

  float sl[8];
#pragma unroll
  for (int p = 0; p < 8; ++p) {
    float e = __expf(sc[p] - m[p]);
    se[tid][p] = e;
    sl[p] = e;
  }
#pragma unroll
  for (int o = 32; o; o >>= 1)
#pragma unroll
    for (int p = 0; p < 8; ++p) sl[p] += __shfl_xor(sl[p], o);
  if ((tid & 63) == 0)
#pragma unroll
    for (int p = 0; p < 8; ++p) rl[tid >> 6][p] = sl[p];
  __syncthreads();
  if (tid < 8) {
    float l = rl[0][tid] + rl[1][tid] + rl[2][tid] + rl[3][tid];
    pm[(size_t)(bh * TCH + tc) * 8 + tid] = m[tid];
    pl[(size_t)(bh * TCH + tc) * 8 + tid] = l;
  }

  const int p  = tid >> 5;
  const int dg = tid & 7;
  const int to = (tid >> 3) & 3;
  const bf16* vb = v + ((size_t)bh * SEQ + t0 + to) * DH + dg * 8;
  float a8[8] = {};
  for (int tl = to; tl < TCL; tl += 4) {
    float wgt = se[tl][p];
    bf16x8 v8 = *(const bf16x8*)(vb + (size_t)(tl - to) * DH);
#pragma unroll
    for (int e = 0; e < 8; ++e) a8[e] += wgt * (float)v8[e];
  }
#pragma unroll
  for (int e = 0; e < 8; ++e) pr[to][p][dg * 8 + e] = a8[e];
  __syncthreads();
  if (to == 0) {
    float* o = pva + ((size_t)(bh * TCH + tc) * 8 + p) * DH + dg * 8;
#pragma unroll
    for (int e = 0; e < 8; ++e)
      o[e] = pr[0][p][dg * 8 + e] + pr[1][p][dg * 8 + e] +
             pr[2][p][dg * 8 + e] + pr[3][p][dg * 8 + e];
  }
}

// ---------------- combine chunk partials -> v_agent[bh][p][d] ----------------
__global__ void combine_vag(const float* __restrict__ pm, const float* __restrict__ pl,
                            const float* __restrict__ pva, float* __restrict__ vag) {
  int bh = blockIdx.x;
#pragma unroll
  for (int e = threadIdx.x; e < 512; e += 256) {
    int p = e >> 6, d = e & 63;
    float M = -1e30f;
#pragma unroll
    for (int tc = 0; tc < TCH; ++tc)
      M = fmaxf(M, pm[(size_t)(bh * TCH + tc) * 8 + p]);
    float L = 0.f, acc = 0.f;
#pragma unroll
    for (int tc = 0; tc < TCH; ++tc) {
      float w = __expf(pm[(size_t)(bh * TCH + tc) * 8 + p] - M);
      L   += w * pl[(size_t)(bh * TCH + tc) * 8 + p];
      acc += w * pva[((size_t)(bh * TCH + tc) * 8 + p) * DH + d];
    }
    vag[(size_t)bh * 512 + e] = acc / L;
  }
}

// ---- W2T[b][n][hp] = sum_d vag[b][hp][d] * WoT[n][h*64+d]  (bf16 out) ----
__global__ void w2_build(const float* __restrict__ vag, const bf16* __restrict__ WoT,
                         bf16* __restrict__ W2T) {
  int b = blockIdx.y;
  int n = blockIdx.x * 16 + (threadIdx.x & 15);
  int h = threadIdx.x >> 4;
  __shared__ float vg[128][65];
  for (int i = threadIdx.x; i < 128 * 64; i += 256)
    vg[i >> 6][i & 63] = vag[(size_t)b * 128 * 64 + i];
  __syncthreads();
  float acc[8] = {};
  const bf16* wrow = WoT + (size_t)n * DIMV + h * 64;
#pragma unroll
  for (int dv = 0; dv < 8; ++dv) {
    bf16x8 wv = *(const bf16x8*)(wrow + dv * 8);
#pragma unroll
    for (int e = 0; e < 8; ++e) {
      float wf = (float)wv[e];
      int d = dv * 8 + e;
#pragma unroll
      for (int p = 0; p < 8; ++p) acc[p] += vg[h * 8 + p][d] * wf;
    }
  }
  bf16x8 o;
#pragma unroll
  for (int p = 0; p < 8; ++p) o[p] = (bf16)acc[p];
  *(bf16x8*)&W2T[((size_t)b * DIMV + n) * HP + h * 8] = o;
}

// ---- P2[b*4096+t][h*8+p] = softmax_p(q . agent * SCALE)  (bf16) ----
__global__ __launch_bounds__(256)
void p2_build(const bf16* __restrict__ q, const float* __restrict__ agentSum,
              bf16* __restrict__ P2) {
  const int bh = blockIdx.y;
  const int t  = blockIdx.x * 256 + threadIdx.x;
  const int tid = threadIdx.x;

  __shared__ float agT[64][8];
  for (int i = tid; i < 512; i += 256) {
    int p = i >> 6, d = i & 63;
    agT[d][p] = agentSum[(size_t)bh * 512 + i] * AGS_F;
  }
  __syncthreads();

  const bf16* qrow = q + ((size_t)bh * SEQ + t) * DH;
  float sc[8] = {};
#pragma unroll
  for (int dc = 0; dc < 8; ++dc) {
    bf16x8 q8 = *(const bf16x8*)(qrow + dc * 8);
#pragma unroll
    for (int e = 0; e < 8; ++e) {
      float qv = (float)q8[e];
      int d = dc * 8 + e;
      float4 a0 = *(const float4*)&agT[d][0];
      float4 a1 = *(const float4*)&agT[d][4];
      sc[0] += a0.x * qv; sc[1] += a0.y * qv; sc[2] += a0.z * qv; sc[3] += a0.w * qv;
      sc[4] += a1.x * qv; sc[5] += a1.y * qv; sc[6] += a1.z * qv; sc[7] += a1.w * qv;
    }
  }
  float m = sc[0];
#pragma unroll
  for (int p = 1; p < 8; ++p) m = fmaxf(m, sc[p]);
  float wsum = 0.f, wgt[8];
#pragma unroll
  for (int p = 0; p < 8; ++p) { wgt[p] = __expf(sc[p] - m); wsum += wgt[p]; }
  float inv = 1.0f / wsum;
  int b = bh >> 4, h = bh & 15;
  bf16x8 o8;
#pragma unroll
  for (int p = 0; p < 8; ++p) o8[p] = (bf16)(wgt[p] * inv);
  *(bf16x8*)&P2[((size_t)(b * SEQ + t)) * HP + h * 8] = o8;
}

extern "C" void kernel_launch(void* const* d_in, const int* in_sizes, int n_in,
                              void* d_out, int out_size, void* d_ws, size_t ws_size,
                              hipStream_t stream) {
  const float* x    = (const float*)d_in[0];   // [4,4096,1024] fp32
  const float* Wqkv = (const float*)d_in[1];   // [1024,3072]   fp32
  const float* Wo   = (const float*)d_in[2];   // [1024,1024]   fp32
  const float* bo   = (const float*)d_in[3];   // [1024]        fp32
  float* out = (float*)d_out;                  // [4,4096,1024] fp32

  char* ws = (char*)d_ws;
  bf16* WqkvT = (bf16*)ws;                                   ws += (size_t)QKV_N * DIMV * 2;
  bf16* WoT   = (bf16*)ws;                                   ws += (size_t)DIMV * DIMV * 2;
  bf16* qkv   = (bf16*)ws;                                   ws += 3 * QKVSZ * 2;
  char* wsu   = ws;                                          ws += (size_t)M_TOTAL * DIMV * 2;
  bf16*  xb    = (bf16*)wsu;
  bf16*  P2    = (bf16*)wsu;                                  // 4 MB (after xb dead)
  bf16*  W2T   = (bf16*)(wsu + (size_t)M_TOTAL * HP * 2);     // 1 MB
  float* agent = (float*)ws;                                 ws += 512 * 64 * 4;
  float* pm    = (float*)ws;                                 ws += BH * TCH * 8 * 4;
  float* pl    = (float*)ws;                                 ws += BH * TCH * 8 * 4;
  float* pva   = (float*)ws;                                 ws += (size_t)BH * TCH * 8 * DH * 4;
  float* vag   = (float*)ws;                                 ws += 512 * 64 * 4;

  const bf16* qp = qkv;
  const bf16* kp = qkv + QKVSZ;
  const bf16* vp = qkv + 2 * QKVSZ;

  // agent accumulated by GEMM1-epilogue atomics -> zero it first
  hipMemsetAsync(agent, 0, 512 * 64 * 4, stream);

  convert_x<<<(size_t)M_TOTAL * DIMV / (256 * 8), 256, 0, stream>>>(x, xb);
  transpose_f32_bf16<<<dim3(QKV_N / 32, DIMV / 32), 256, 0, stream>>>(Wqkv, WqkvT, DIMV, QKV_N);
  transpose_f32_bf16<<<dim3(DIMV / 32, DIMV / 32), 256, 0, stream>>>(Wo, WoT, DIMV, DIMV);

  // GEMM1: qkv = x @ Wqkv (split planes) + fused q pooling sums
  // 256^2 tile, 8-phase counted-vmcnt schedule: grid 768 = (3072/256)*(16384/256)
  gemm1_qkv<<<768, 512, 0, stream>>>(xb, WqkvT, qkv, agent);

  p2_build<<<dim3(SEQ / 256, BH), 256, 0, stream>>>(qp, agent, P2);
  stage1_fused<<<dim3(TCH, BH), 256, 0, stream>>>(kp, vp, agent, pm, pl, pva);
  combine_vag<<<BH, 256, 0, stream>>>(pm, pl, pva, vag);
  w2_build<<<dim3(DIMV / 16, BATCH), 256, 0, stream>>>(vag, WoT, W2T);

  // out = P2 @ W2T(batched) + bo   (fp32 out, K=128)
  gemm_bt<2><<<dim3(DIMV / 128, M_TOTAL / 128), 256, 0, stream>>>(
      P2, W2T, (void*)out, bo, nullptr, M_TOTAL, DIMV, HP);
}